// Round 6
// baseline (383.701 us; speedup 1.0000x reference)
//
#include <hip/hip_runtime.h>

#define BN_EPS 1e-5f

typedef __attribute__((ext_vector_type(8))) short short8;
typedef __attribute__((ext_vector_type(4))) float floatx4;

#define GLL(gp, lp)                                                            \
    __builtin_amdgcn_global_load_lds(                                          \
        (const __attribute__((address_space(1))) void*)(gp),                   \
        (__attribute__((address_space(3))) void*)(lp), 16, 0, 0)

__device__ inline unsigned short f2bf(float f) {
    unsigned int u = __float_as_uint(f);
    unsigned int r = (u + 0x7FFF + ((u >> 16) & 1)) >> 16;  // RNE
    return (unsigned short)r;
}

__device__ inline float bf2f(unsigned short u) {
    return __uint_as_float(((unsigned int)u) << 16);
}

// Software grid barrier: one counter slot per use, pre-zeroed each launch.
// Release: threadfence + device-scope atomicAdd. Acquire: atomic spin + fence.
__device__ inline void grid_bar(int* ctr, int nblocks) {
    __syncthreads();
    if (threadIdx.x == 0) {
        __threadfence();
        atomicAdd(ctr, 1);
        while (atomicAdd(ctr, 0) < nblocks) { __builtin_amdgcn_s_sleep(2); }
        __threadfence();
    }
    __syncthreads();
}

// ---------------- fused CSR construction (1 kernel, 5 barriers) ----------------
// grid = 256 blocks x 256 threads (co-resident on 256 CUs).

__global__ __launch_bounds__(256) void setup_kernel(
    const int* __restrict__ row, const int* __restrict__ col,
    int* __restrict__ cnt, float* __restrict__ dis,
    int* __restrict__ rowptr, int* __restrict__ cursor, int* __restrict__ adj,
    int* __restrict__ bsum, int* __restrict__ ctrs, int N, int E) {
    int b = blockIdx.x, t = threadIdx.x, nb = gridDim.x;
    int gid = b * 256 + t, gsz = nb * 256;

    // P0: zero cnt
    for (int i = gid; i < N; i += gsz) cnt[i] = 0;
    grid_bar(&ctrs[0], nb);

    // P1: count in-degree
    for (int e = gid; e < E; e += gsz) atomicAdd(&cnt[col[e]], 1);
    grid_bar(&ctrs[1], nb);

    // P2: dis + block-local inclusive scan of this block's segment
    for (int i = gid; i < N; i += gsz) dis[i] = rsqrtf((float)(cnt[i] + 1));
    int per = (N + nb - 1) / nb;        // 40 for N=10000
    int s0 = b * per;
    int s1 = min(s0 + per, N);
    __shared__ int sc[256];
    int v = (t < s1 - s0) ? cnt[s0 + t] : 0;
    sc[t] = v;
    __syncthreads();
    for (int o = 1; o < 256; o <<= 1) {
        int u = (t >= o) ? sc[t - o] : 0;
        __syncthreads();
        sc[t] += u;
        __syncthreads();
    }
    if (t == 255) bsum[b] = sc[255];
    grid_bar(&ctrs[2], nb);

    // P3: block 0 scans the 256 block sums (inclusive)
    if (b == 0) {
        __shared__ int sb[256];
        sb[t] = bsum[t];
        __syncthreads();
        for (int o = 1; o < 256; o <<= 1) {
            int u = (t >= o) ? sb[t - o] : 0;
            __syncthreads();
            sb[t] += u;
            __syncthreads();
        }
        bsum[t] = sb[t];
    }
    grid_bar(&ctrs[3], nb);

    // P4: write exclusive rowptr + cursor
    int boff = (b == 0) ? 0 : bsum[b - 1];
    if (t < s1 - s0) {
        int ex = boff + sc[t] - v;
        rowptr[s0 + t] = ex;
        cursor[s0 + t] = ex;
    }
    if (b == nb - 1 && t == 0) rowptr[N] = bsum[nb - 1];
    grid_bar(&ctrs[4], nb);

    // P5: scatter edges into CSR
    for (int e = gid; e < E; e += gsz) {
        int pos = atomicAdd(&cursor[col[e]], 1);
        adj[pos] = row[e];
    }
}

// ---------------- fused fp32 -> bf16 conversion (x, W1, W2) ----------------

__global__ void f2b_all_kernel(const float* __restrict__ x, const float* __restrict__ W1,
                               const float* __restrict__ W2, ushort* __restrict__ xbf,
                               ushort* __restrict__ W1bf, ushort* __restrict__ W2bf,
                               int n4x, int n4w) {
    int i = blockIdx.x * blockDim.x + threadIdx.x;
    const float* src;
    ushort* dst;
    int j;
    if (i < n4x) { src = x; dst = xbf; j = i; }
    else if (i < n4x + n4w) { src = W1; dst = W1bf; j = i - n4x; }
    else if (i < n4x + 2 * n4w) { src = W2; dst = W2bf; j = i - n4x - n4w; }
    else return;
    float4 v = ((const float4*)src)[j];
    ushort4 o;
    o.x = f2bf(v.x); o.y = f2bf(v.y); o.z = f2bf(v.z); o.w = f2bf(v.w);
    ((ushort4*)dst)[j] = o;
}

// ---------------- MFMA GEMM: C[M,N] = A[M,K] @ B[N,K]^T (bf16 in) ----------

template <bool OUT_BF16>
__global__ __launch_bounds__(256) void gemm_mfma_kernel(
    const ushort* __restrict__ A, const ushort* __restrict__ B,
    void* __restrict__ Cout, int M, int N, int K) {
    __shared__ ushort As[128 * 32];
    __shared__ ushort Bs[128 * 32];
    int tid = threadIdx.x;
    int wave = tid >> 6;
    int lane = tid & 63;
    int quad = lane >> 4;
    int l15 = lane & 15;
    int m0 = blockIdx.y * 128;
    int n0 = blockIdx.x * 128;

    int srow = lane >> 2;
    int skoff = (lane & 3) * 8;

    floatx4 acc[4][4];
#pragma unroll
    for (int i = 0; i < 4; i++)
#pragma unroll
        for (int j = 0; j < 4; j++) acc[i][j] = (floatx4){0.f, 0.f, 0.f, 0.f};

    int wm = (wave & 1) * 64;
    int wn = (wave >> 1) * 64;

    for (int k0 = 0; k0 < K; k0 += 32) {
#pragma unroll
        for (int cc = 0; cc < 2; cc++) {
            int c = wave * 2 + cc;
            int arow = m0 + c * 16 + srow;
            arow = min(arow, M - 1);
            const ushort* ga = A + (size_t)arow * K + k0 + skoff;
            GLL(ga, (char*)As + c * 1024);
            int brow = n0 + c * 16 + srow;
            const ushort* gb = B + (size_t)brow * K + k0 + skoff;
            GLL(gb, (char*)Bs + c * 1024);
        }
        __syncthreads();

        short8 af[4], bfr[4];
#pragma unroll
        for (int i = 0; i < 4; i++) {
            int r = wm + i * 16 + l15;
            af[i] = *(const short8*)(As + r * 32 + quad * 8);
        }
#pragma unroll
        for (int j = 0; j < 4; j++) {
            int r = wn + j * 16 + l15;
            bfr[j] = *(const short8*)(Bs + r * 32 + quad * 8);
        }
#pragma unroll
        for (int i = 0; i < 4; i++)
#pragma unroll
            for (int j = 0; j < 4; j++)
                acc[i][j] = __builtin_amdgcn_mfma_f32_16x16x32_bf16(af[i], bfr[j], acc[i][j], 0, 0, 0);
        __syncthreads();
    }

#pragma unroll
    for (int i = 0; i < 4; i++) {
#pragma unroll
        for (int r = 0; r < 4; r++) {
            int row = m0 + wm + i * 16 + quad * 4 + r;
            if (row < M) {
                if (OUT_BF16) {
                    ushort* cp = (ushort*)Cout + (size_t)row * N + n0 + wn + l15;
#pragma unroll
                    for (int j = 0; j < 4; j++) cp[j * 16] = f2bf(acc[i][j][r]);
                } else {
                    float* cp = (float*)Cout + (size_t)row * N + n0 + wn + l15;
#pragma unroll
                    for (int j = 0; j < 4; j++) cp[j * 16] = acc[i][j][r];
                }
            }
        }
    }
}

// ---------------- bf16 gather, C=256 channels ----------------

template <bool OUT_BF16>
__global__ __launch_bounds__(256) void gather_bf_kernel(
    const ushort* __restrict__ xl, const int* __restrict__ rowptr,
    const int* __restrict__ adj, const float* __restrict__ dis,
    void* __restrict__ h) {
    int v = blockIdx.x;
    int wave = threadIdx.x >> 6;
    int lane = threadIdx.x & 63;
    float dv = dis[v];

    float acc[4] = {0.f, 0.f, 0.f, 0.f};
    int e0 = rowptr[v], e1 = rowptr[v + 1];
    for (int e = e0 + wave; e < e1; e += 4) {
        int r = adj[e];
        float wgt = dis[r] * dv;
        ushort4 u = ((const ushort4*)xl)[(size_t)r * 64 + lane];
        acc[0] = fmaf(bf2f(u.x), wgt, acc[0]);
        acc[1] = fmaf(bf2f(u.y), wgt, acc[1]);
        acc[2] = fmaf(bf2f(u.z), wgt, acc[2]);
        acc[3] = fmaf(bf2f(u.w), wgt, acc[3]);
    }

    __shared__ float4 red[4][64];
    red[wave][lane] = make_float4(acc[0], acc[1], acc[2], acc[3]);
    __syncthreads();
    if (wave == 0) {
        float4 s = red[0][lane];
        float4 b = red[1][lane];
        float4 c = red[2][lane];
        float4 d = red[3][lane];
        s.x += b.x + c.x + d.x;
        s.y += b.y + c.y + d.y;
        s.z += b.z + c.z + d.z;
        s.w += b.w + c.w + d.w;
        ushort4 u = ((const ushort4*)xl)[(size_t)v * 64 + lane];
        float w2 = dv * dv;
        s.x = fmaf(bf2f(u.x), w2, s.x);
        s.y = fmaf(bf2f(u.y), w2, s.y);
        s.z = fmaf(bf2f(u.z), w2, s.z);
        s.w = fmaf(bf2f(u.w), w2, s.w);
        if (OUT_BF16) {
            ushort4 o;
            o.x = f2bf(s.x); o.y = f2bf(s.y); o.z = f2bf(s.z); o.w = f2bf(s.w);
            ((ushort4*)h)[(size_t)v * 64 + lane] = o;
        } else {
            ((float4*)h)[(size_t)v * 64 + lane] = s;
        }
    }
}

// ---------------- fused BN stats + scale/shift + elementwise tail ----------
// grid = 256 blocks. Phase A: per-block partial sum/sumsq over its row range.
// Phase B: one wave per channel reduces partials -> scale/shift.
// Phase C: MODE 0: h1 -> BN+ReLU+bf16 cast (writes obf)
//          MODE 1: out = relu(bn(h) + x)    (writes fout)

template <int MODE>
__global__ __launch_bounds__(256) void bn_fused_kernel(
    const float* __restrict__ h, const float* __restrict__ gamma,
    const float* __restrict__ beta, float* __restrict__ psum,
    float* __restrict__ psumsq, float* __restrict__ scale,
    float* __restrict__ shift, ushort* __restrict__ obf,
    const float* __restrict__ xres, float* __restrict__ fout,
    int* __restrict__ ctrs, int N, int IC) {
    int nb = gridDim.x;             // 256
    int b = blockIdx.x, t = threadIdx.x;
    int groups = IC >> 2;           // 128 or 64
    int rpi = 256 / groups;
    int g = t & (groups - 1);
    int ro = t / groups;
    int per = (N + nb - 1) / nb;
    int r0 = b * per;
    int r1 = min(r0 + per, N);

    // Phase A: partials
    float4 s = make_float4(0.f, 0.f, 0.f, 0.f);
    float4 q = make_float4(0.f, 0.f, 0.f, 0.f);
    for (int r = r0 + ro; r < r1; r += rpi) {
        float4 v = *(const float4*)(h + (size_t)r * IC + g * 4);
        s.x += v.x; s.y += v.y; s.z += v.z; s.w += v.w;
        q.x += v.x * v.x; q.y += v.y * v.y; q.z += v.z * v.z; q.w += v.w * v.w;
    }
    {
        __shared__ float4 redS[256];
        __shared__ float4 redQ[256];
        redS[t] = s;
        redQ[t] = q;
        __syncthreads();
        if (ro == 0) {
            for (int i = 1; i < rpi; i++) {
                float4 o = redS[t + i * groups];
                s.x += o.x; s.y += o.y; s.z += o.z; s.w += o.w;
                float4 p = redQ[t + i * groups];
                q.x += p.x; q.y += p.y; q.z += p.z; q.w += p.w;
            }
            psum[(size_t)(4 * g + 0) * nb + b] = s.x;
            psum[(size_t)(4 * g + 1) * nb + b] = s.y;
            psum[(size_t)(4 * g + 2) * nb + b] = s.z;
            psum[(size_t)(4 * g + 3) * nb + b] = s.w;
            psumsq[(size_t)(4 * g + 0) * nb + b] = q.x;
            psumsq[(size_t)(4 * g + 1) * nb + b] = q.y;
            psumsq[(size_t)(4 * g + 2) * nb + b] = q.z;
            psumsq[(size_t)(4 * g + 3) * nb + b] = q.w;
        }
    }
    grid_bar(&ctrs[0], nb);

    // Phase B: reduce -> scale/shift (wave per channel)
    {
        int wave = t >> 6, lane = t & 63;
        int c = b * 4 + wave;
        if (c < IC) {
            float ss = 0.f, qq = 0.f;
            for (int k = lane; k < nb; k += 64) {
                ss += psum[(size_t)c * nb + k];
                qq += psumsq[(size_t)c * nb + k];
            }
#pragma unroll
            for (int o = 32; o > 0; o >>= 1) {
                ss += __shfl_down(ss, o, 64);
                qq += __shfl_down(qq, o, 64);
            }
            if (lane == 0) {
                float invN = 1.0f / (float)N;
                float mean = ss * invN;
                float var = qq * invN - mean * mean;
                float sc = gamma[c] * rsqrtf(var + BN_EPS);
                scale[c] = sc;
                shift[c] = beta[c] - mean * sc;
            }
        }
    }
    grid_bar(&ctrs[1], nb);

    // Phase C: elementwise tail (grid-stride)
    int total4 = (N * IC) / 4;
    int gid = b * 256 + t, gsz = nb * 256;
    int IC4 = IC >> 2;
    for (int i = gid; i < total4; i += gsz) {
        int c4 = (i & (IC4 - 1)) * 4;
        float4 v = ((const float4*)h)[i];
        if (MODE == 0) {
            ushort4 o;
            o.x = f2bf(fmaxf(fmaf(v.x, scale[c4 + 0], shift[c4 + 0]), 0.f));
            o.y = f2bf(fmaxf(fmaf(v.y, scale[c4 + 1], shift[c4 + 1]), 0.f));
            o.z = f2bf(fmaxf(fmaf(v.z, scale[c4 + 2], shift[c4 + 2]), 0.f));
            o.w = f2bf(fmaxf(fmaf(v.w, scale[c4 + 3], shift[c4 + 3]), 0.f));
            ((ushort4*)obf)[i] = o;
        } else {
            float4 xv = ((const float4*)xres)[i];
            float4 o;
            o.x = fmaxf(fmaf(v.x, scale[c4 + 0], shift[c4 + 0]) + xv.x, 0.f);
            o.y = fmaxf(fmaf(v.y, scale[c4 + 1], shift[c4 + 1]) + xv.y, 0.f);
            o.z = fmaxf(fmaf(v.z, scale[c4 + 2], shift[c4 + 2]) + xv.z, 0.f);
            o.w = fmaxf(fmaf(v.w, scale[c4 + 3], shift[c4 + 3]) + xv.w, 0.f);
            ((float4*)fout)[i] = o;
        }
    }
}

// ---------------- launch ----------------

extern "C" void kernel_launch(void* const* d_in, const int* in_sizes, int n_in,
                              void* d_out, int out_size, void* d_ws, size_t ws_size,
                              hipStream_t stream) {
    const float* x  = (const float*)d_in[0];
    const int*   es = (const int*)d_in[1];
    const float* W1 = (const float*)d_in[2];
    const float* g1 = (const float*)d_in[3];
    const float* b1 = (const float*)d_in[4];
    const float* W2 = (const float*)d_in[5];
    const float* g2 = (const float*)d_in[6];
    const float* b2 = (const float*)d_in[7];
    float* out = (float*)d_out;

    const int E  = in_sizes[1] / 2;
    const int IC = in_sizes[3];   // 512
    const int C  = in_sizes[7];   // 256
    const int N  = in_sizes[0] / C;
    const int NB = 256;           // fused-kernel grid (co-resident)

    const int* row = es;
    const int* col = es + E;

    // ---- workspace layout ----
    char* w = (char*)d_ws;
    size_t off = 0;
    auto alloc = [&](size_t bytes) -> void* {
        void* p = w + off;
        off = (off + bytes + 255) & ~(size_t)255;
        return p;
    };
    int*   ctrs    = (int*)alloc(16 * 4);                     // barrier counters
    int*   cnt     = (int*)alloc((size_t)N * 4);
    float* dis     = (float*)alloc((size_t)N * 4);
    int*   rowptr  = (int*)alloc((size_t)(N + 1) * 4);
    int*   cursor  = (int*)alloc((size_t)N * 4);
    int*   adj     = (int*)alloc((size_t)E * 4);
    int*   bsum    = (int*)alloc((size_t)NB * 4);
    float* psum    = (float*)alloc((size_t)IC * NB * 4);
    float* psumsq  = (float*)alloc((size_t)IC * NB * 4);
    float* scale1  = (float*)alloc((size_t)IC * 4);
    float* shift1  = (float*)alloc((size_t)IC * 4);
    float* scale2  = (float*)alloc((size_t)C * 4);
    float* shift2  = (float*)alloc((size_t)C * 4);
    ushort* xbf    = (ushort*)alloc((size_t)N * C * 2);
    ushort* W1bf   = (ushort*)alloc((size_t)IC * C * 2);
    ushort* W2bf   = (ushort*)alloc((size_t)IC * C * 2);
    ushort* g1x    = (ushort*)alloc((size_t)N * C * 2);
    float*  h1     = (float*)alloc((size_t)N * IC * 4);
    ushort* h1bf   = (ushort*)alloc((size_t)N * IC * 2);
    ushort* xl2bf  = (ushort*)alloc((size_t)N * C * 2);
    float*  h2     = (float*)alloc((size_t)N * C * 4);

    // ---- zero barrier counters (only required init) ----
    hipMemsetAsync(ctrs, 0, 16 * 4, stream);

    // ---- CSR build (1 fused kernel) ----
    setup_kernel<<<NB, 256, 0, stream>>>(row, col, cnt, dis, rowptr, cursor, adj,
                                         bsum, ctrs, N, E);

    // ---- bf16 conversions (1 fused kernel) ----
    {
        int n4x = N * C / 4, n4w = IC * C / 4;
        int tot = n4x + 2 * n4w;
        f2b_all_kernel<<<(tot + 255) / 256, 256, 0, stream>>>(x, W1, W2, xbf, W1bf, W2bf, n4x, n4w);
    }

    // ---- layer 1: g1x = A_norm(x); h1 = g1x @ W1^T; bn1+relu+cast ----
    gather_bf_kernel<true><<<N, 256, 0, stream>>>(xbf, rowptr, adj, dis, g1x);
    {
        dim3 grid(IC / 128, (N + 127) / 128);
        gemm_mfma_kernel<false><<<grid, 256, 0, stream>>>(g1x, W1bf, h1, N, IC, C);
    }
    bn_fused_kernel<0><<<NB, 256, 0, stream>>>(h1, g1, b1, psum, psumsq, scale1, shift1,
                                               h1bf, nullptr, nullptr, ctrs + 5, N, IC);

    // ---- layer 2: xl2 = h1bf @ W2^T (bf16); h2 = A_norm(xl2); bn2+res+relu ----
    {
        dim3 grid(C / 128, (N + 127) / 128);
        gemm_mfma_kernel<true><<<grid, 256, 0, stream>>>(h1bf, W2bf, xl2bf, N, C, IC);
    }
    gather_bf_kernel<false><<<N, 256, 0, stream>>>(xl2bf, rowptr, adj, dis, h2);
    bn_fused_kernel<1><<<NB, 256, 0, stream>>>(h2, g2, b2, psum, psumsq, scale2, shift2,
                                               nullptr, x, out, ctrs + 7, N, C);
}